// Round 6
// baseline (163.699 us; speedup 1.0000x reference)
//
#include <hip/hip_runtime.h>
#include <hip/hip_bf16.h>

// Problem constants
#define DIM_X 256
#define DIM_E 256
#define DD    512          // DIM_X + DIM_E
#define NB    8            // batch
#define NN    2048         // sequence
#define SCALE 0.044194173824159216f   // (DIM_X+DIM_E)^-0.5
#define GRID  512          // 2 blocks/CU x 256 CU, fully resident

typedef __attribute__((ext_vector_type(8))) __bf16 bf16x8;
typedef __attribute__((ext_vector_type(4))) float  f32x4;
using bf16 = __hip_bfloat16;

__device__ __forceinline__ unsigned short f2bf(float f) {
  union { __hip_bfloat16 h; unsigned short u; } c;
  c.h = __float2bfloat16(f);
  return c.u;
}

// async global->LDS 16B copy. LDS dest must be wave-uniform base + lane*16.
__device__ __forceinline__ void async_lds16(const void* g, void* l) {
  using u32_as3 = __attribute__((address_space(3))) unsigned int;
  using u32_as1 = const __attribute__((address_space(1))) unsigned int;
  __builtin_amdgcn_global_load_lds(
      reinterpret_cast<u32_as1*>(reinterpret_cast<unsigned long long>(g)),
      reinterpret_cast<u32_as3*>(static_cast<unsigned int>(
          reinterpret_cast<unsigned long long>(l))),
      16, 0, 0);
}

// ---------------------------------------------------------------------------
// Grid barrier v3. R1 (flat+RMW-poll)=108us, R4 (tree+RMW-poll)=123us --
// the INVARIANT component was the poll loop's fetch_add(0) every 64th iter:
// ~500 waiting waves generate a continuous RMW storm on the g_sense line;
// RMWs serialize at the coherence point, so the releaser's flip and the real
// arrivals queue behind thousands of poll-RMWs (~20us/barrier). Fix: poll
// with PLAIN relaxed agent-scope atomic loads (read-shared, no serialization;
// they reach the coherence point -- same pattern as cooperative-groups
// grid.sync), s_sleep(8) pacing, RMW fallback demoted to every-4096 as a
// staleness safety net. Tree arrivals kept (16 buckets x 32 + 1 global).
// Sense-reversing, self-restoring across graph replays (proven R1/R4).
// ---------------------------------------------------------------------------
#define NBUCKETS 16
#define BUCKET_SZ (GRID / NBUCKETS)  // 32
__device__ __align__(128) unsigned g_bcnt[NBUCKETS * 32] = {};
__device__ __align__(128) unsigned g_gcnt  = 0u;
__device__ __align__(128) unsigned g_sense = 0u;

__device__ __forceinline__ void grid_sync(int bx) {
  __syncthreads();  // each wave drains its own vmcnt/lgkm before s_barrier
  if (threadIdx.x == 0) {
    unsigned s = __hip_atomic_load(&g_sense, __ATOMIC_RELAXED,
                                   __HIP_MEMORY_SCOPE_AGENT);
    unsigned* bc = &g_bcnt[(bx & (NBUCKETS - 1)) * 32];
    unsigned prev = __hip_atomic_fetch_add(bc, 1u, __ATOMIC_ACQ_REL,
                                           __HIP_MEMORY_SCOPE_AGENT);
    if (prev == BUCKET_SZ - 1) {           // last of bucket
      __hip_atomic_store(bc, 0u, __ATOMIC_RELAXED, __HIP_MEMORY_SCOPE_AGENT);
      unsigned gp = __hip_atomic_fetch_add(&g_gcnt, 1u, __ATOMIC_ACQ_REL,
                                           __HIP_MEMORY_SCOPE_AGENT);
      if (gp == NBUCKETS - 1) {            // last bucket
        __hip_atomic_store(&g_gcnt, 0u, __ATOMIC_RELAXED,
                           __HIP_MEMORY_SCOPE_AGENT);
        __hip_atomic_store(&g_sense, s ^ 1u, __ATOMIC_RELEASE,
                           __HIP_MEMORY_SCOPE_AGENT);
      }
    }
    unsigned n = 0;
    for (;;) {
      unsigned v = __hip_atomic_load(&g_sense, __ATOMIC_RELAXED,
                                     __HIP_MEMORY_SCOPE_AGENT);
      if (v != s) break;
      if ((++n & 4095u) == 0u)             // rare coherence-forcing fallback
        (void)__hip_atomic_fetch_add(&g_sense, 0u, __ATOMIC_RELAXED,
                                     __HIP_MEMORY_SCOPE_AGENT);
      __builtin_amdgcn_s_sleep(8);
    }
    __builtin_amdgcn_fence(__ATOMIC_ACQUIRE, "agent");
  }
  __syncthreads();
}

// ---------------------------------------------------------------------------
// One BMxBN tile of C = alpha * Acat @ Bcat^T (operands K-major bf16).
// Proven dbuf version (rounds 2-5): 4 waves 2x2, 16x16x32 MFMA, XOR-swizzled
// LDS, global_load_lds width-16 staging, stage(t+1) before compute(t), one
// barrier per K-step. smem = 2*(BM+BN)*BKt*2 bytes.
// ---------------------------------------------------------------------------
template <int BM, int BN, int BKt, bool OUT_BF16, int ASPLIT, int BSPLIT>
__device__ void gemm_tile(const bf16* __restrict__ A0,
                          const bf16* __restrict__ A1,
                          const bf16* __restrict__ B0,
                          const bf16* __restrict__ B1, void* __restrict__ Cv,
                          int K, int lda, int ldb, int ldc, float alpha,
                          char* smem) {
  constexpr int CPT  = BKt / 8;
  constexpr int KS   = BKt / 32;
  constexpr int WTM  = BM / 2, WTN = BN / 2;
  constexpr int IM   = WTM / 16, IN = WTN / 16;
  constexpr int CA   = BM * CPT, CB = BN * CPT;
  constexpr int BUFB = (BM + BN) * BKt * 2;

  const int tid  = threadIdx.x;
  const int lane = tid & 63;
  const int wave = tid >> 6;
  const int lm   = lane & 15;
  const int quad = lane >> 4;
  const int wm   = (wave >> 1) * WTM;
  const int wn   = (wave & 1) * WTN;

  auto stage = [&](int t, int buf) {
    const int k0 = t * BKt;
    const bf16* Ak = A0; int ka = k0;
    if (ASPLIT > 0 && k0 >= ASPLIT) { Ak = A1; ka = k0 - ASPLIT; }
    const bf16* Bk = B0; int kb = k0;
    if (BSPLIT > 0 && k0 >= BSPLIT) { Bk = B1; kb = k0 - BSPLIT; }
    bf16* sA = (bf16*)(smem + (size_t)buf * BUFB);
    bf16* sB = sA + BM * BKt;
#pragma unroll
    for (int c = tid; c < CA; c += 256) {
      int row = c / CPT;
      int cb  = (c % CPT) ^ (row % CPT);
      async_lds16(Ak + (long)row * lda + ka + cb * 8, sA + (size_t)c * 8);
    }
#pragma unroll
    for (int c = tid; c < CB; c += 256) {
      int row = c / CPT;
      int cb  = (c % CPT) ^ (row % CPT);
      async_lds16(Bk + (long)row * ldb + kb + cb * 8, sB + (size_t)c * 8);
    }
  };

  f32x4 acc[IM][IN];
#pragma unroll
  for (int i = 0; i < IM; i++)
#pragma unroll
    for (int j = 0; j < IN; j++) acc[i][j] = (f32x4){0.f, 0.f, 0.f, 0.f};

  const int nt = K / BKt;
  stage(0, 0);
  __syncthreads();
  int cur = 0;
  for (int t = 0; t < nt; ++t) {
    if (t + 1 < nt) stage(t + 1, cur ^ 1);
    const bf16* sA = (const bf16*)(smem + (size_t)cur * BUFB);
    const bf16* sB = sA + BM * BKt;
    bf16x8 af[KS][IM], bfr[KS][IN];
#pragma unroll
    for (int s = 0; s < KS; s++) {
#pragma unroll
      for (int i = 0; i < IM; i++) {
        int r = wm + i * 16 + lm;
        af[s][i] = *(const bf16x8*)&sA[r * BKt +
                                       (((s * 4 + quad) ^ (r % CPT)) * 8)];
      }
#pragma unroll
      for (int j = 0; j < IN; j++) {
        int r = wn + j * 16 + lm;
        bfr[s][j] = *(const bf16x8*)&sB[r * BKt +
                                        (((s * 4 + quad) ^ (r % CPT)) * 8)];
      }
    }
#pragma unroll
    for (int s = 0; s < KS; s++)
#pragma unroll
      for (int i = 0; i < IM; i++)
#pragma unroll
        for (int j = 0; j < IN; j++)
          acc[i][j] = __builtin_amdgcn_mfma_f32_16x16x32_bf16(
              af[s][i], bfr[s][j], acc[i][j], 0, 0, 0);
    __syncthreads();
    cur ^= 1;
  }

  // C/D layout (16x16): col = lane&15, row = (lane>>4)*4 + reg  [m89-verified]
  const int baseRow = wm + quad * 4;
  const int baseCol = wn + lm;
  if (OUT_BF16) {
    bf16* Cb = (bf16*)Cv;
#pragma unroll
    for (int i = 0; i < IM; i++)
#pragma unroll
      for (int r = 0; r < 4; r++) {
        int row = baseRow + i * 16 + r;
#pragma unroll
        for (int j = 0; j < IN; j++)
          Cb[(long)row * ldc + baseCol + j * 16] =
              __float2bfloat16(acc[i][j][r] * alpha);
      }
  } else {
    float* Cf = (float*)Cv;
#pragma unroll
    for (int i = 0; i < IM; i++)
#pragma unroll
      for (int r = 0; r < 4; r++) {
        int row = baseRow + i * 16 + r;
#pragma unroll
        for (int j = 0; j < IN; j++)
          Cf[(long)row * ldc + baseCol + j * 16] = acc[i][j][r] * alpha;
      }
  }
}

// pack job descriptor (R0-proven block-cooperative 32x32 tile pack)
struct PackJob {
  const float* src; int ld;
  bf16* dS; int ldS;
  bf16* dT; int ldT;
};

// ---------------------------------------------------------------------------
// Fused pipeline v3: one launch, 512 blocks, 3 load-poll tree barriers.
//   phase0: pack, 5120 jobs grid-strided (10/block), block-cooperative LDS
//           tile (R0-proven), next-job global load issued BEFORE the current
//           job's barriers (hides ~700ns L3/HBM latency under the 2 syncs).
//           x-jobs XCD-affine: job j<4096 has b=j&7 and runs on block j&511,
//           so (j&7)==(bx&7) -- VT_b/xb_b land in XCD b's L2 (R5 mapping).
//   phase1: blocks 0-255: M half-K partials, 128x64 tiles, K=1024
//           (R3/R5-verified); blocks 256-319: W2T = WqT@WkT^T (R3-verified);
//           blocks 320-511 idle at the barrier.
//   phase2: 512 blocks, R = SCALE*(M1+M2)@W2T^T K-concat (verified R1-R5).
//   phase3: 512 blocks, out = [xb|eb] @ R^T, 64x128 tiles (R2-verified).
// All phases <=48KB LDS; launch_bounds(256,2) -> all 512 blocks resident.
// ---------------------------------------------------------------------------
__global__ __launch_bounds__(256, 2) void fused3_k(
    const float* __restrict__ x, const float* __restrict__ e,
    const float* __restrict__ Wq, const float* __restrict__ Wk,
    bf16* __restrict__ xb, bf16* __restrict__ VT, bf16* __restrict__ eb,
    bf16* __restrict__ ET, bf16* __restrict__ WqT, bf16* __restrict__ WkT,
    bf16* __restrict__ W2T, bf16* __restrict__ M1, bf16* __restrict__ M2,
    bf16* __restrict__ R, float* __restrict__ out) {
  __shared__ __align__(16) char smem[49152];
  const int bx  = blockIdx.x;
  const int tid = threadIdx.x;

  // ---- phase 0: pack -----------------------------------------------------
  {
    float (*tile)[33] = reinterpret_cast<float (*)[33]>(smem);
    const int lrow = tid >> 3;        // 0..31
    const int lc4  = (tid & 7) * 4;   // float4 col
    auto desc = [&](int j) -> PackJob {
      PackJob P;
      if (j < 4096) {
        int b = j & 7;                // XCD-affine (R5)
        int slot = j >> 3;
        int r = slot >> 3, c = slot & 7;
        P.src = x + ((long)b * NN + r * 32) * DIM_X + c * 32; P.ld = DIM_X;
        P.dS = xb + ((long)b * NN + r * 32) * DIM_X + c * 32; P.ldS = DIM_X;
        P.dT = VT + ((long)b * DIM_X + c * 32) * NN + r * 32; P.ldT = NN;
      } else if (j < 4608) {
        int i = j - 4096, r = i >> 3, c = i & 7;
        P.src = e + ((long)r * 32) * DIM_E + c * 32; P.ld = DIM_E;
        P.dS = eb + ((long)r * 32) * DIM_E + c * 32; P.ldS = DIM_E;
        P.dT = ET + ((long)c * 32) * NN + r * 32; P.ldT = NN;
      } else if (j < 4864) {
        int i = j - 4608, r = i >> 4, c = i & 15;
        P.src = Wq + ((long)r * 32) * DD + c * 32; P.ld = DD;
        P.dS = nullptr; P.ldS = 0;
        P.dT = WqT + ((long)c * 32) * DD + r * 32; P.ldT = DD;
      } else {
        int i = j - 4864, r = i >> 4, c = i & 15;
        P.src = Wk + ((long)r * 32) * DD + c * 32; P.ld = DD;
        P.dS = nullptr; P.ldS = 0;
        P.dT = WkT + ((long)c * 32) * DD + r * 32; P.ldT = DD;
      }
      return P;
    };
    PackJob P = desc(bx);
    float4 v = *(const float4*)(P.src + (long)lrow * P.ld + lc4);
    for (int j = bx; j < 5120; j += GRID) {
      PackJob Pn; float4 vn;
      const bool more = (j + GRID) < 5120;
      if (more) {                      // issue next-job load NOW (overlaps
        Pn = desc(j + GRID);           //  both __syncthreads below)
        vn = *(const float4*)(Pn.src + (long)lrow * Pn.ld + lc4);
      }
      if (P.dS) {
        ushort4 o;
        o.x = f2bf(v.x); o.y = f2bf(v.y); o.z = f2bf(v.z); o.w = f2bf(v.w);
        *(ushort4*)((unsigned short*)P.dS + (long)lrow * P.ldS + lc4) = o;
      }
      tile[lrow][lc4 + 0] = v.x; tile[lrow][lc4 + 1] = v.y;
      tile[lrow][lc4 + 2] = v.z; tile[lrow][lc4 + 3] = v.w;
      __syncthreads();
      {
        ushort4 o;
        o.x = f2bf(tile[lc4 + 0][lrow]);
        o.y = f2bf(tile[lc4 + 1][lrow]);
        o.z = f2bf(tile[lc4 + 2][lrow]);
        o.w = f2bf(tile[lc4 + 3][lrow]);
        *(ushort4*)((unsigned short*)P.dT + (long)lrow * P.ldT + lc4) = o;
      }
      __syncthreads();
      if (more) { P = Pn; v = vn; }
    }
  }
  grid_sync(bx);

  // ---- phase 1: M split-K partials (R3/R5-verified) + W2T ---------------
  if (bx < 256) {
    const int b   = bx & 7;
    const int idx = bx >> 3;              // 0..31
    const int kh  = idx & 1;              // K half
    const int mt  = (idx >> 1) & 1;       // row tile (2 x 128 = 256)
    const int nt  = idx >> 2;             // col tile (8 x 64 = 512)
    const bf16* A = VT + (long)b * DIM_X * NN + (long)mt * 128 * NN +
                    kh * 1024;
    const bf16* B = (nt < 4)
        ? VT + (long)b * DIM_X * NN + (long)nt * 64 * NN + kh * 1024
        : ET + (long)(nt - 4) * 64 * NN + kh * 1024;
    bf16* C = (kh ? M2 : M1) + (long)b * DIM_X * DD + (long)mt * 128 * DD +
              nt * 64;
    gemm_tile<128, 64, 64, true, 0, 0>(A, nullptr, B, nullptr, C, 1024, NN,
                                       NN, DD, 1.0f, smem);
  } else if (bx < 320) {
    const int i = bx - 256;
    int r2 = i >> 3, c2 = i & 7;
    gemm_tile<64, 64, 64, true, 0, 0>(
        WqT + (long)r2 * 64 * DD, nullptr, WkT + (long)c2 * 64 * DD, nullptr,
        W2T + (long)r2 * 64 * DD + c2 * 64, DD, DD, DD, DD, 1.0f, smem);
  }
  grid_sync(bx);

  // ---- phase 2: R = SCALE * (M1+M2) @ W2T^T (K-concat, verified) --------
  {
    const int b = bx & 7, r = (bx >> 3) & 7, c = bx >> 6;
    const bf16* a0 = M1 + (long)b * DIM_X * DD + (long)r * 32 * DD;
    const bf16* a1 = M2 + (long)b * DIM_X * DD + (long)r * 32 * DD;
    const bf16* w  = W2T + (long)c * 64 * DD;
    gemm_tile<32, 64, 128, true, 512, 512>(
        a0, a1, w, w,
        R + (long)b * DIM_X * DD + (long)r * 32 * DD + c * 64, 1024, DD, DD,
        DD, SCALE, smem);
  }
  grid_sync(bx);

  // ---- phase 3: out = [xb|eb] @ R^T (R2-verified 64x128, fp32 out) ------
  {
    const int b = bx & 7, m = (bx >> 3) & 31, n = (bx >> 8) & 1;
    gemm_tile<64, 128, 64, false, 256, 0>(
        xb + (long)b * NN * DIM_X + (long)m * 64 * DIM_X,
        eb + (long)m * 64 * DIM_E,
        R + (long)b * DIM_X * DD + (long)n * 128 * DD, nullptr,
        out + (long)b * NN * DIM_X + (long)m * 64 * DIM_X + n * 128, DD,
        DIM_X, DD, DIM_X, 1.0f, smem);
  }
}

// ---------------------------------------------------------------------------

extern "C" void kernel_launch(void* const* d_in, const int* in_sizes, int n_in,
                              void* d_out, int out_size, void* d_ws,
                              size_t ws_size, hipStream_t stream) {
  const float* x  = (const float*)d_in[0];  // (8, 2048, 256)
  const float* e  = (const float*)d_in[1];  // (2048, 256)
  const float* Wq = (const float*)d_in[2];  // (512, 512)
  const float* Wk = (const float*)d_in[3];  // (512, 512)
  float* out = (float*)d_out;               // (8, 2048, 256)

  char* ws = (char*)d_ws;
  size_t off = 0;
  auto alloc = [&](size_t bytes) {
    void* p = ws + off;
    off += (bytes + 255) & ~(size_t)255;
    return p;
  };

  bf16* xb  = (bf16*)alloc((size_t)NB * NN * DIM_X * 2);  // 8.4 MB
  bf16* VT  = (bf16*)alloc((size_t)NB * DIM_X * NN * 2);  // 8.4 MB
  bf16* eb  = (bf16*)alloc((size_t)NN * DIM_E * 2);       // 1 MB
  bf16* ET  = (bf16*)alloc((size_t)DIM_E * NN * 2);       // 1 MB
  bf16* WqT = (bf16*)alloc((size_t)DD * DD * 2);          // 0.5 MB
  bf16* WkT = (bf16*)alloc((size_t)DD * DD * 2);          // 0.5 MB
  bf16* W2T = (bf16*)alloc((size_t)DD * DD * 2);          // 0.5 MB
  bf16* M1  = (bf16*)alloc((size_t)NB * DIM_X * DD * 2);  // 2 MB
  bf16* M2  = (bf16*)alloc((size_t)NB * DIM_X * DD * 2);  // 2 MB
  bf16* R   = (bf16*)alloc((size_t)NB * DIM_X * DD * 2);  // 2 MB

  fused3_k<<<GRID, 256, 0, stream>>>(x, e, Wq, Wk, xb, VT, eb, ET, WqT, WkT,
                                     W2T, M1, M2, R, out);
}